// Round 2
// baseline (216.636 us; speedup 1.0000x reference)
//
#include <hip/hip_runtime.h>
#include <hip/hip_bf16.h>

#define NN 4096
#define LOG2E 1.44269504088896340736f
#define SPLITS 8

typedef __attribute__((ext_vector_type(8))) short s8v;   // 8 x bf16
typedef __attribute__((ext_vector_type(4))) float f4v;   // mfma accumulator

__device__ __forceinline__ unsigned fu(float x){ union{float f;unsigned u;}z; z.f=x; return z.u; }
// pack two floats to bf16x2 by truncation (bias cancels in acc/l ratio)
__device__ __forceinline__ unsigned pack2(float a, float b){
  return __builtin_amdgcn_perm(fu(b), fu(a), 0x07060302u);
}
__device__ __forceinline__ unsigned short f2bf_rne(float x){
  unsigned u = fu(x);
  u += 0x7fffu + ((u >> 16) & 1u);
  return (unsigned short)(u >> 16);
}

// Kernel 1: h = x@W (fp32), write Vt[c][j] (bf16, transposed),
// el' (x LOG2E) and factorized exponentials Qr=exp2(er'), Sr=exp2(0.2*er').
__global__ __launch_bounds__(256) void k1_proj(
    const float* __restrict__ x, const float* __restrict__ W,
    const float* __restrict__ a, unsigned short* __restrict__ Vt,
    float* __restrict__ el4, float* __restrict__ Qr, float* __restrict__ Sr)
{
  __shared__ float4 xs[512];           // 8 rows x 256 cols fp32
  const int t = threadIdx.x;
  const int r0 = blockIdx.x * 8;
  const float4* xg = (const float4*)(x + (size_t)r0 * 256);
  xs[t] = xg[t];
  xs[t + 256] = xg[t + 256];
  __syncthreads();

  float acc[8] = {0.f,0.f,0.f,0.f,0.f,0.f,0.f,0.f};
  const float* Wp = W + t;             // column c = t
  #pragma unroll 2
  for (int k4 = 0; k4 < 64; ++k4) {
    float w0 = Wp[(k4*4+0)*256];
    float w1 = Wp[(k4*4+1)*256];
    float w2 = Wp[(k4*4+2)*256];
    float w3 = Wp[(k4*4+3)*256];
    #pragma unroll
    for (int r = 0; r < 8; ++r) {
      float4 xv = xs[r*64 + k4];       // broadcast LDS read
      acc[r] = fmaf(xv.x, w0, acc[r]);
      acc[r] = fmaf(xv.y, w1, acc[r]);
      acc[r] = fmaf(xv.z, w2, acc[r]);
      acc[r] = fmaf(xv.w, w3, acc[r]);
    }
  }

  // Vt write: thread t holds 8 consecutive-j values of column c=t -> one 16B store
  union { unsigned u[4]; s8v v; } pk;
  #pragma unroll
  for (int p = 0; p < 4; ++p)
    pk.u[p] = (unsigned)f2bf_rne(acc[2*p]) | ((unsigned)f2bf_rne(acc[2*p+1]) << 16);
  *(s8v*)(Vt + (size_t)t * NN + r0) = pk.v;

  // el/er: wave w == head h; lane f = t&63
  const int f = t & 63, h = t >> 6;
  const float al = a[f], ar = a[64 + f];
  #pragma unroll
  for (int r = 0; r < 8; ++r) {
    float v = acc[r] * al;
    float u = acc[r] * ar;
    #pragma unroll
    for (int off = 32; off > 0; off >>= 1) {
      v += __shfl_xor(v, off);
      u += __shfl_xor(u, off);
    }
    if (f == 0) {
      el4[(r0 + r) * 4 + h] = v * LOG2E;                     // [i][h] raw (x LOG2E)
      float up = u * LOG2E;
      Qr[h * NN + (r0 + r)] = __builtin_amdgcn_exp2f(up);        // [h][j]
      Sr[h * NN + (r0 + r)] = __builtin_amdgcn_exp2f(0.2f * up); // [h][j]
    }
  }
}

// Kernel 2: fused mask+lrelu+exp (factorized) + PV GEMM via MFMA.
// grid (128 i-tiles of 32 rows, SPLITS j-chunks of 512), block 256 = 4 waves.
// wave w: row sub-tile rw = w&1 (16 rows), head pair hw = w>>1 (heads 2hw,2hw+1).
// lane: m = l&15 (row in tile), q = l>>4 (k-quad).
__global__ __launch_bounds__(256, 4) void k2_attn(
    const float* __restrict__ adj, const unsigned short* __restrict__ Vt,
    const float* __restrict__ el4, const float* __restrict__ Qr,
    const float* __restrict__ Sr, float* __restrict__ accP,
    float* __restrict__ lP)
{
  const int t = threadIdx.x;
  const int w = t >> 6, l = t & 63;
  const int m = l & 15, q = l >> 4;
  const int rw = w & 1, hw = w >> 1;
  const int i0 = blockIdx.x * 32;
  const int split = blockIdx.y;
  const int i = i0 + rw * 16 + m;
  const int h0 = hw * 2;

  const float el0 = el4[i * 4 + h0];
  const float el1 = el4[i * 4 + h0 + 1];
  const float P[2] = { __builtin_amdgcn_exp2f(el0), __builtin_amdgcn_exp2f(el1) };
  const float R[2] = { __builtin_amdgcn_exp2f(0.2f * el0), __builtin_amdgcn_exp2f(0.2f * el1) };

  f4v acc[2][4];
  #pragma unroll
  for (int hh = 0; hh < 2; ++hh)
    #pragma unroll
    for (int nf = 0; nf < 4; ++nf)
      acc[hh][nf] = (f4v){0.f, 0.f, 0.f, 0.f};
  f4v accL[2] = { (f4v){0.f,0.f,0.f,0.f}, (f4v){0.f,0.f,0.f,0.f} };

  // all-ones bf16 B fragment: row-sum trick for l
  union { unsigned u[4]; s8v v; } ones;
  #pragma unroll
  for (int p = 0; p < 4; ++p) ones.u[p] = 0x3F803F80u;

  const float* arow = adj + (size_t)i * NN;
  int j0 = split * 512 + q * 8;

  float4 a0 = *(const float4*)(arow + j0);
  float4 a1 = *(const float4*)(arow + j0 + 4);

  #pragma unroll 1
  for (int jc = 0; jc < 16; ++jc) {
    const int jn = (jc < 15) ? (j0 + 32) : j0;  // guard last-iter OOB on row 4095
    float4 na0 = *(const float4*)(arow + jn);
    float4 na1 = *(const float4*)(arow + jn + 4);

    #pragma unroll
    for (int hh = 0; hh < 2; ++hh) {
      const int h = h0 + hh;
      const float* qp = Qr + h * NN + j0;
      const float* sp = Sr + h * NN + j0;
      float4 q0 = *(const float4*)(qp);
      float4 q1 = *(const float4*)(qp + 4);
      float4 sv0 = *(const float4*)(sp);
      float4 sv1 = *(const float4*)(sp + 4);
      const float Ph = P[hh], Rh = R[hh];
      float s0 = a0.x * fmaxf(Ph * q0.x, Rh * sv0.x);
      float s1 = a0.y * fmaxf(Ph * q0.y, Rh * sv0.y);
      float s2 = a0.z * fmaxf(Ph * q0.z, Rh * sv0.z);
      float s3 = a0.w * fmaxf(Ph * q0.w, Rh * sv0.w);
      float s4 = a1.x * fmaxf(Ph * q1.x, Rh * sv1.x);
      float s5 = a1.y * fmaxf(Ph * q1.y, Rh * sv1.y);
      float s6 = a1.z * fmaxf(Ph * q1.z, Rh * sv1.z);
      float s7 = a1.w * fmaxf(Ph * q1.w, Rh * sv1.w);
      union { unsigned u[4]; s8v v; } A;   // A-frag: row m, k = q*8+idx
      A.u[0] = pack2(s0, s1);
      A.u[1] = pack2(s2, s3);
      A.u[2] = pack2(s4, s5);
      A.u[3] = pack2(s6, s7);
      const unsigned short* vb = Vt + (size_t)(h * 64 + m) * NN + j0;
      #pragma unroll
      for (int nf = 0; nf < 4; ++nf) {
        s8v B = *(const s8v*)(vb + (size_t)nf * 16 * NN);  // B-frag: col n=m, k=q*8+idx
        acc[hh][nf] = __builtin_amdgcn_mfma_f32_16x16x32_bf16(A.v, B, acc[hh][nf], 0, 0, 0);
      }
      accL[hh] = __builtin_amdgcn_mfma_f32_16x16x32_bf16(A.v, ones.v, accL[hh], 0, 0, 0);
    }
    j0 += 32;
    a0 = na0; a1 = na1;
  }

  // epilogue: C/D layout col = m, row = q*4 + reg
  float* ap = accP + (size_t)split * NN * 256;
  #pragma unroll
  for (int hh = 0; hh < 2; ++hh)
    #pragma unroll
    for (int nf = 0; nf < 4; ++nf)
      #pragma unroll
      for (int r = 0; r < 4; ++r) {
        int row = i0 + rw * 16 + q * 4 + r;
        int col = (h0 + hh) * 64 + nf * 16 + m;
        ap[(size_t)row * 256 + col] = acc[hh][nf][r];
      }
  // l partials: accL[hh][r] = row-sum for row q*4+r (all cols equal); m==0 lanes write
  if (m == 0) {
    #pragma unroll
    for (int hh = 0; hh < 2; ++hh)
      #pragma unroll
      for (int r = 0; r < 4; ++r) {
        int row = i0 + rw * 16 + q * 4 + r;
        lP[((size_t)split * NN + row) * 4 + h0 + hh] = accL[hh][r];
      }
  }
}

// Kernel 3: combine split partials, divide by l, mean over heads.
__global__ __launch_bounds__(256) void k3_reduce(
    const float* __restrict__ accP, const float* __restrict__ lP,
    float* __restrict__ out)
{
  int tid = blockIdx.x * 256 + threadIdx.x;  // 262144 threads
  int i = tid >> 6, f = tid & 63;
  float o = 0.f;
  #pragma unroll
  for (int h = 0; h < 4; ++h) {
    float sa = 0.f, sl = 0.f;
    #pragma unroll
    for (int s = 0; s < SPLITS; ++s) {
      sa += accP[((size_t)s * NN + i) * 256 + h * 64 + f];
      sl += lP[((size_t)s * NN + i) * 4 + h];
    }
    o += sa / sl;   // sl > 0 guaranteed: diagonal of adj is 1
  }
  out[tid] = 0.25f * o;
}

extern "C" void kernel_launch(void* const* d_in, const int* in_sizes, int n_in,
                              void* d_out, int out_size, void* d_ws, size_t ws_size,
                              hipStream_t stream) {
  const float* x   = (const float*)d_in[0];   // (4096, 256)
  const float* adj = (const float*)d_in[1];   // (4096, 4096)
  const float* W   = (const float*)d_in[2];   // (256, 256)
  const float* a   = (const float*)d_in[3];   // (128, 1)
  float* out = (float*)d_out;                 // (4096, 64)

  char* ws = (char*)d_ws;
  unsigned short* Vt = (unsigned short*)ws;                       // 2 MB  bf16 [256][4096]
  float* el4 = (float*)(ws + (2u << 20));                         // 64 KB [4096][4]
  float* Qr  = (float*)(ws + (2u << 20) + (64u << 10));           // 64 KB [4][4096]
  float* Sr  = (float*)(ws + (2u << 20) + (128u << 10));          // 64 KB [4][4096]
  float* lP  = (float*)(ws + (2u << 20) + (192u << 10));          // 512 KB [8][4096][4]
  float* accP= (float*)(ws + (2u << 20) + (192u << 10) + (512u << 10)); // 32 MB [8][4096][256]

  k1_proj<<<512, 256, 0, stream>>>(x, W, a, Vt, el4, Qr, Sr);
  k2_attn<<<dim3(128, SPLITS), 256, 0, stream>>>(adj, Vt, el4, Qr, Sr, accP, lP);
  k3_reduce<<<1024, 256, 0, stream>>>(accP, lP, out);
}

// Round 3
// 209.954 us; speedup vs baseline: 1.0318x; 1.0318x over previous
//
#include <hip/hip_runtime.h>
#include <hip/hip_bf16.h>

#define NN 4096
#define LOG2E 1.44269504088896340736f
#define SPLITS 8

typedef __attribute__((ext_vector_type(8))) short s8v;   // 8 x bf16
typedef __attribute__((ext_vector_type(4))) float f4v;   // mfma accumulator

__device__ __forceinline__ unsigned fu(float x){ union{float f;unsigned u;}z; z.f=x; return z.u; }
// pack two floats to bf16x2 by truncation (bias cancels in acc/l ratio)
__device__ __forceinline__ unsigned pack2(float a, float b){
  return __builtin_amdgcn_perm(fu(b), fu(a), 0x07060302u);
}
__device__ __forceinline__ unsigned short f2bf_rne(float x){
  unsigned u = fu(x);
  u += 0x7fffu + ((u >> 16) & 1u);
  return (unsigned short)(u >> 16);
}

// Kernel 1: h = x@W (fp32), write Vt[c][j] (bf16, transposed),
// el' (x LOG2E) and factorized exponentials Qr=exp2(er'), Sr=exp2(0.2*er').
// W loads software-pipelined (prefetch next k4 group).
__global__ __launch_bounds__(256) void k1_proj(
    const float* __restrict__ x, const float* __restrict__ W,
    const float* __restrict__ a, unsigned short* __restrict__ Vt,
    float* __restrict__ el4, float* __restrict__ Qr, float* __restrict__ Sr)
{
  __shared__ float4 xs[512];           // 8 rows x 256 cols fp32
  const int t = threadIdx.x;
  const int r0 = blockIdx.x * 8;
  const float4* xg = (const float4*)(x + (size_t)r0 * 256);
  xs[t] = xg[t];
  xs[t + 256] = xg[t + 256];
  __syncthreads();

  float acc[8] = {0.f,0.f,0.f,0.f,0.f,0.f,0.f,0.f};
  const float* Wp = W + t;             // column c = t
  float w0 = Wp[0], w1 = Wp[256], w2 = Wp[512], w3 = Wp[768];
  #pragma unroll 1
  for (int k4 = 0; k4 < 64; ++k4) {
    const int kn = (k4 + 1) & 63;      // wrap: last prefetch reads valid memory
    float nw0 = Wp[kn*1024 +   0];
    float nw1 = Wp[kn*1024 + 256];
    float nw2 = Wp[kn*1024 + 512];
    float nw3 = Wp[kn*1024 + 768];
    #pragma unroll
    for (int r = 0; r < 8; ++r) {
      float4 xv = xs[r*64 + k4];       // broadcast LDS read
      acc[r] = fmaf(xv.x, w0, acc[r]);
      acc[r] = fmaf(xv.y, w1, acc[r]);
      acc[r] = fmaf(xv.z, w2, acc[r]);
      acc[r] = fmaf(xv.w, w3, acc[r]);
    }
    w0 = nw0; w1 = nw1; w2 = nw2; w3 = nw3;
  }

  // Vt write: thread t holds 8 consecutive-j values of column c=t -> one 16B store
  union { unsigned u[4]; s8v v; } pk;
  #pragma unroll
  for (int p = 0; p < 4; ++p)
    pk.u[p] = (unsigned)f2bf_rne(acc[2*p]) | ((unsigned)f2bf_rne(acc[2*p+1]) << 16);
  *(s8v*)(Vt + (size_t)t * NN + r0) = pk.v;

  // el/er: wave w == head h; lane f = t&63
  const int f = t & 63, h = t >> 6;
  const float al = a[f], ar = a[64 + f];
  #pragma unroll
  for (int r = 0; r < 8; ++r) {
    float v = acc[r] * al;
    float u = acc[r] * ar;
    #pragma unroll
    for (int off = 32; off > 0; off >>= 1) {
      v += __shfl_xor(v, off);
      u += __shfl_xor(u, off);
    }
    if (f == 0) {
      el4[(r0 + r) * 4 + h] = v * LOG2E;                     // [i][h] (x LOG2E)
      float up = u * LOG2E;
      Qr[h * NN + (r0 + r)] = __builtin_amdgcn_exp2f(up);        // [h][j]
      Sr[h * NN + (r0 + r)] = __builtin_amdgcn_exp2f(0.2f * up); // [h][j]
    }
  }
}

// Kernel 2: fused mask+lrelu+exp (factorized) + PV GEMM via MFMA.
// grid (128 i-tiles of 32 rows, SPLITS j-chunks of 512), block 256 = 4 waves.
// wave w: i-subtile sub = w&1 (16 rows), j-half = w>>1 (256 of the 512 chunk).
// Each wave does ALL 4 heads (max loads/iteration). Halves merged via LDS.
// lane: m = l&15 (row), q = l>>4 (k-quad).
__global__ __launch_bounds__(256, 4) void k2_attn(
    const float* __restrict__ adj, const unsigned short* __restrict__ Vt,
    const float* __restrict__ el4, const float* __restrict__ Qr,
    const float* __restrict__ Sr, float* __restrict__ accP,
    float* __restrict__ lP)
{
  __shared__ float red[128 * 68];      // 34.8 KB: 2 writer waves x 64 lanes x 64 floats (stride 68)
  const int t = threadIdx.x;
  const int w = t >> 6, l = t & 63;
  const int m = l & 15, q = l >> 4;
  const int sub = w & 1, half = w >> 1;
  const int i0 = blockIdx.x * 32;
  const int split = blockIdx.y;
  const int i = i0 + sub * 16 + m;

  float4 elv = *(const float4*)(el4 + i * 4);
  const float P[4] = { __builtin_amdgcn_exp2f(elv.x), __builtin_amdgcn_exp2f(elv.y),
                       __builtin_amdgcn_exp2f(elv.z), __builtin_amdgcn_exp2f(elv.w) };
  const float R[4] = { __builtin_amdgcn_exp2f(0.2f*elv.x), __builtin_amdgcn_exp2f(0.2f*elv.y),
                       __builtin_amdgcn_exp2f(0.2f*elv.z), __builtin_amdgcn_exp2f(0.2f*elv.w) };

  f4v acc[4][4];
  #pragma unroll
  for (int h = 0; h < 4; ++h)
    #pragma unroll
    for (int nf = 0; nf < 4; ++nf)
      acc[h][nf] = (f4v){0.f, 0.f, 0.f, 0.f};
  f4v accL[4] = {(f4v){0.f,0.f,0.f,0.f},(f4v){0.f,0.f,0.f,0.f},
                 (f4v){0.f,0.f,0.f,0.f},(f4v){0.f,0.f,0.f,0.f}};

  union { unsigned u[4]; s8v v; } ones;   // all-ones bf16 B: row-sum trick for l
  #pragma unroll
  for (int p = 0; p < 4; ++p) ones.u[p] = 0x3F803F80u;

  const float* arow = adj + (size_t)i * NN;
  int j0 = split * 512 + half * 256 + q * 8;

  float4 a0 = *(const float4*)(arow + j0);
  float4 a1 = *(const float4*)(arow + j0 + 4);

  #pragma unroll 1
  for (int jc = 0; jc < 8; ++jc) {
    const int jn = (jc < 7) ? (j0 + 32) : j0;   // guard last-iter OOB on row 4095
    float4 na0 = *(const float4*)(arow + jn);
    float4 na1 = *(const float4*)(arow + jn + 4);

    #pragma unroll
    for (int h = 0; h < 4; ++h) {
      const float* qp = Qr + h * NN + j0;
      const float* sp = Sr + h * NN + j0;
      float4 q0 = *(const float4*)(qp);
      float4 q1 = *(const float4*)(qp + 4);
      float4 sv0 = *(const float4*)(sp);
      float4 sv1 = *(const float4*)(sp + 4);
      const float Ph = P[h], Rh = R[h];
      float s0 = a0.x * fmaxf(Ph * q0.x, Rh * sv0.x);
      float s1 = a0.y * fmaxf(Ph * q0.y, Rh * sv0.y);
      float s2 = a0.z * fmaxf(Ph * q0.z, Rh * sv0.z);
      float s3 = a0.w * fmaxf(Ph * q0.w, Rh * sv0.w);
      float s4 = a1.x * fmaxf(Ph * q1.x, Rh * sv1.x);
      float s5 = a1.y * fmaxf(Ph * q1.y, Rh * sv1.y);
      float s6 = a1.z * fmaxf(Ph * q1.z, Rh * sv1.z);
      float s7 = a1.w * fmaxf(Ph * q1.w, Rh * sv1.w);
      union { unsigned u[4]; s8v v; } A;   // A-frag: row m, k = q*8+idx
      A.u[0] = pack2(s0, s1);
      A.u[1] = pack2(s2, s3);
      A.u[2] = pack2(s4, s5);
      A.u[3] = pack2(s6, s7);
      const unsigned short* vb = Vt + (size_t)(h * 64 + m) * NN + j0;
      #pragma unroll
      for (int nf = 0; nf < 4; ++nf) {
        s8v B = *(const s8v*)(vb + (size_t)nf * 16 * NN);  // B-frag: col n=m, k=q*8+idx
        acc[h][nf] = __builtin_amdgcn_mfma_f32_16x16x32_bf16(A.v, B, acc[h][nf], 0, 0, 0);
      }
      accL[h] = __builtin_amdgcn_mfma_f32_16x16x32_bf16(A.v, ones.v, accL[h], 0, 0, 0);
    }
    j0 += 32;
    a0 = na0; a1 = na1;
  }

  // l partials per (split, half): no cross-wave merge needed.
  // C/D layout: col = m (lane&15), row = q*4 + r; m==0 lanes hold all 16 rows.
  if (m == 0) {
    #pragma unroll
    for (int h = 0; h < 4; ++h)
      #pragma unroll
      for (int r = 0; r < 4; ++r) {
        int row = i0 + sub * 16 + q * 4 + r;
        lP[((size_t)(split * 2 + half) * NN + row) * 4 + h] = accL[h][r];
      }
  }

  // Cross-wave merge of acc: waves 2,3 (half=1) dump to LDS; waves 0,1 add+store.
  if (w >= 2) {
    const int base = ((w - 2) * 64 + l) * 68;
    #pragma unroll
    for (int h = 0; h < 4; ++h)
      #pragma unroll
      for (int nf = 0; nf < 4; ++nf)
        *(f4v*)(red + base + h * 16 + nf * 4) = acc[h][nf];
  }
  __syncthreads();
  if (w < 2) {
    const int base = (w * 64 + l) * 68;
    float* ap = accP + (size_t)split * NN * 256;
    #pragma unroll
    for (int h = 0; h < 4; ++h)
      #pragma unroll
      for (int nf = 0; nf < 4; ++nf) {
        f4v other = *(const f4v*)(red + base + h * 16 + nf * 4);
        f4v s = acc[h][nf] + other;
        #pragma unroll
        for (int r = 0; r < 4; ++r) {
          int row = i0 + sub * 16 + q * 4 + r;
          int col = h * 64 + nf * 16 + m;
          ap[(size_t)row * 256 + col] = s[r];
        }
      }
  }
}

// Kernel 3: combine split partials, divide by l, mean over heads.
__global__ __launch_bounds__(256) void k3_reduce(
    const float* __restrict__ accP, const float* __restrict__ lP,
    float* __restrict__ out)
{
  int tid = blockIdx.x * 256 + threadIdx.x;  // 262144 threads
  int i = tid >> 6, f = tid & 63;
  float o = 0.f;
  #pragma unroll
  for (int h = 0; h < 4; ++h) {
    float sa = 0.f, sl = 0.f;
    #pragma unroll
    for (int s = 0; s < SPLITS; ++s)
      sa += accP[((size_t)s * NN + i) * 256 + h * 64 + f];
    #pragma unroll
    for (int s = 0; s < 2 * SPLITS; ++s)
      sl += lP[((size_t)s * NN + i) * 4 + h];
    o += sa / sl;   // sl > 0 guaranteed: diagonal of adj is 1
  }
  out[tid] = 0.25f * o;
}

extern "C" void kernel_launch(void* const* d_in, const int* in_sizes, int n_in,
                              void* d_out, int out_size, void* d_ws, size_t ws_size,
                              hipStream_t stream) {
  const float* x   = (const float*)d_in[0];   // (4096, 256)
  const float* adj = (const float*)d_in[1];   // (4096, 4096)
  const float* W   = (const float*)d_in[2];   // (256, 256)
  const float* a   = (const float*)d_in[3];   // (128, 1)
  float* out = (float*)d_out;                 // (4096, 64)

  char* ws = (char*)d_ws;
  unsigned short* Vt = (unsigned short*)ws;                       // 2 MB  bf16 [256][4096]
  float* el4 = (float*)(ws + (2u << 20));                         // 64 KB [4096][4]
  float* Qr  = (float*)(ws + (2u << 20) + (64u << 10));           // 64 KB [4][4096]
  float* Sr  = (float*)(ws + (2u << 20) + (128u << 10));          // 64 KB [4][4096]
  float* lP  = (float*)(ws + (2u << 20) + (192u << 10));          // 1 MB  [16][4096][4]
  float* accP= (float*)(ws + (3u << 20) + (192u << 10));          // 32 MB [8][4096][256]

  k1_proj<<<512, 256, 0, stream>>>(x, W, a, Vt, el4, Qr, Sr);
  k2_attn<<<dim3(128, SPLITS), 256, 0, stream>>>(adj, Vt, el4, Qr, Sr, accP, lP);
  k3_reduce<<<1024, 256, 0, stream>>>(accP, lP, out);
}